// Round 7
// baseline (443.681 us; speedup 1.0000x reference)
//
#include <hip/hip_runtime.h>
#include <stdint.h>
#include <stddef.h>

#define N_NODES 100000
#define N_EDGES 1600000
#define IN_CH 128
#define HID_CH 128
#define OUT_CH 40

#define NB 196            // buckets: b = dst >> 9 (512 nodes each; 196*512 >= 100000)
#define NG 8              // blockIdx%8 sub-groups (approx XCD-local append streams)
#define BCAP 1792         // per-(g,b) capacity; mean 1024, sigma 32 -> +24 sigma

#define N_MASK_WORDS 400000   // 100000*128/32

typedef __attribute__((ext_vector_type(8))) short bf16x8;
typedef __attribute__((ext_vector_type(4))) float f32x4;

// ---------------- bf16 helpers ----------------
__device__ __forceinline__ ushort f2bf(float f) {
    uint32_t u = __float_as_uint(f);
    uint32_t r = (u + 0x7FFFu + ((u >> 16) & 1u)) >> 16;   // RNE
    return (ushort)r;
}
__device__ __forceinline__ float bf2f(ushort u) {
    return __uint_as_float(((uint32_t)u) << 16);
}

// ---------------- threefry2x32 (JAX PRNG, key = (0,42)) ----------------
__device__ __forceinline__ uint32_t rotl32(uint32_t x, int r) {
    return (x << r) | (x >> (32 - r));
}

__device__ __forceinline__ void threefry2x32_k42(uint32_t x0, uint32_t x1,
                                                 uint32_t& o0, uint32_t& o1) {
    const uint32_t ks0 = 0u, ks1 = 42u;
    const uint32_t ks2 = 0u ^ 42u ^ 0x1BD11BDAu;
    x0 += ks0; x1 += ks1;
    x0 += x1; x1 = rotl32(x1, 13); x1 ^= x0;
    x0 += x1; x1 = rotl32(x1, 15); x1 ^= x0;
    x0 += x1; x1 = rotl32(x1, 26); x1 ^= x0;
    x0 += x1; x1 = rotl32(x1,  6); x1 ^= x0;
    x0 += ks1; x1 += ks2 + 1u;
    x0 += x1; x1 = rotl32(x1, 17); x1 ^= x0;
    x0 += x1; x1 = rotl32(x1, 29); x1 ^= x0;
    x0 += x1; x1 = rotl32(x1, 16); x1 ^= x0;
    x0 += x1; x1 = rotl32(x1, 24); x1 ^= x0;
    x0 += ks2; x1 += ks0 + 2u;
    x0 += x1; x1 = rotl32(x1, 13); x1 ^= x0;
    x0 += x1; x1 = rotl32(x1, 15); x1 ^= x0;
    x0 += x1; x1 = rotl32(x1, 26); x1 ^= x0;
    x0 += x1; x1 = rotl32(x1,  6); x1 ^= x0;
    x0 += ks0; x1 += ks1 + 3u;
    x0 += x1; x1 = rotl32(x1, 17); x1 ^= x0;
    x0 += x1; x1 = rotl32(x1, 29); x1 ^= x0;
    x0 += x1; x1 = rotl32(x1, 16); x1 ^= x0;
    x0 += x1; x1 = rotl32(x1, 24); x1 ^= x0;
    x0 += ks1; x1 += ks2 + 4u;
    x0 += x1; x1 = rotl32(x1, 13); x1 ^= x0;
    x0 += x1; x1 = rotl32(x1, 15); x1 ^= x0;
    x0 += x1; x1 = rotl32(x1, 26); x1 ^= x0;
    x0 += x1; x1 = rotl32(x1,  6); x1 ^= x0;
    x0 += ks2; x1 += ks0 + 5u;
    o0 = x0; o1 = x1;
}

// Precompute dropout bits: word w, bit j  <->  element idx = w*32+j
// (idx = row*128 + col).  bit==1 means DROP.  (Same bits as validated
// rounds 3-6: partitionable threefry, bits = o0^o1, drop iff MSB set.)
__global__ __launch_bounds__(256) void dropout_mask(uint32_t* __restrict__ mask) {
    int w = blockIdx.x * blockDim.x + threadIdx.x;
    if (w >= N_MASK_WORDS) return;
    uint32_t m = 0;
    #pragma unroll 4
    for (int j = 0; j < 32; ++j) {
        uint32_t o0, o1;
        threefry2x32_k42(0u, (uint32_t)w * 32u + j, o0, o1);
        m |= ((o0 ^ o1) >> 31) << j;
    }
    mask[w] = m;
}

// ---------------- edge dtype detection ----------------
__global__ void detect_int64(const int* __restrict__ ei32, int* __restrict__ flag) {
    int i = blockIdx.x * blockDim.x + threadIdx.x;
    int stride = gridDim.x * blockDim.x;
    int local = 0;
    for (int k = i; k < N_EDGES; k += stride) local |= ei32[2 * k + 1];
    if (local) atomicOr(flag, 1);
}

__device__ __forceinline__ void load_edge(const void* ei, bool is32, int e,
                                          int& s, int& d) {
    if (is32) {
        const int* p = (const int*)ei;
        s = p[e]; d = p[N_EDGES + e];
    } else {
        const long long* p = (const long long*)ei;
        s = (int)p[e]; d = (int)p[N_EDGES + e];
    }
}

__global__ void zero_i32(int* __restrict__ p, int n) {
    int i = blockIdx.x * blockDim.x + threadIdx.x;
    int stride = gridDim.x * blockDim.x;
    for (; i < n; i += stride) p[i] = 0;
}

// ---------------- bucketed CSR build ----------------
__global__ __launch_bounds__(256) void bucket_edges(
    const void* __restrict__ ei, const int* __restrict__ flag,
    int* __restrict__ gcnt, uint2* __restrict__ gbuf) {
    bool is32 = (*flag != 0);
    int g = blockIdx.x & (NG - 1);
    int i = blockIdx.x * blockDim.x + threadIdx.x;
    int stride = gridDim.x * blockDim.x;
    for (; i < N_EDGES; i += stride) {
        int s, d;
        load_edge(ei, is32, i, s, d);
        int b = d >> 9;
        int pos = atomicAdd(&gcnt[(g * NB + b) * 16], 1);
        gbuf[(size_t)(g * NB + b) * BCAP + pos] = make_uint2((uint32_t)s, (uint32_t)d);
    }
}

__global__ void bucket_scan(const int* __restrict__ gcnt, int* __restrict__ bbase) {
    __shared__ int s[256];
    int t = threadIdx.x;
    int tot = 0;
    if (t < NB)
        for (int g = 0; g < NG; ++g) tot += gcnt[(g * NB + t) * 16];
    s[t] = tot;
    __syncthreads();
    for (int off = 1; off < 256; off <<= 1) {
        int a = (t >= off) ? s[t - off] : 0;
        __syncthreads();
        s[t] += a;
        __syncthreads();
    }
    if (t < NB) bbase[t] = s[t] - tot;   // exclusive
}

__global__ __launch_bounds__(256) void build_csr(
    const int* __restrict__ gcnt, const uint2* __restrict__ gbuf,
    const int* __restrict__ bbase, int* __restrict__ csr, int* __restrict__ cursor) {
    __shared__ int hist[512];
    __shared__ int excl[512];
    __shared__ int cur[512];
    __shared__ int psum[256];
    const int b = blockIdx.x;
    const int t = threadIdx.x;
    hist[t] = 0; hist[t + 256] = 0;
    __syncthreads();
    const int base = bbase[b];
    for (int g = 0; g < NG; ++g) {
        int cnt = gcnt[(g * NB + b) * 16];
        const uint2* src = gbuf + (size_t)(g * NB + b) * BCAP;
        for (int i = t; i < cnt; i += 256)
            atomicAdd(&hist[src[i].y & 511], 1);
    }
    __syncthreads();
    int h0 = hist[2 * t], h1 = hist[2 * t + 1];
    psum[t] = h0 + h1;
    __syncthreads();
    int v = psum[t];
    for (int off = 1; off < 256; off <<= 1) {
        int a = (t >= off) ? psum[t - off] : 0;
        __syncthreads();
        psum[t] += a;
        __syncthreads();
    }
    int pex = psum[t] - v;
    excl[2 * t] = pex;
    excl[2 * t + 1] = pex + h0;
    cur[2 * t] = pex;
    cur[2 * t + 1] = pex + h0;
    __syncthreads();
    for (int j = t; j < 512; j += 256) {
        int node = b * 512 + j;
        if (node < N_NODES) cursor[node] = base + excl[j] + hist[j];
    }
    for (int g = 0; g < NG; ++g) {
        int cnt = gcnt[(g * NB + b) * 16];
        const uint2* src = gbuf + (size_t)(g * NB + b) * BCAP;
        for (int i = t; i < cnt; i += 256) {
            uint2 p = src[i];
            int pos = atomicAdd(&cur[p.y & 511], 1);
            csr[base + pos] = (int)p.x;
        }
    }
}

// ---------------- conversions ----------------
__global__ void cvt_f32_bf16(const float* __restrict__ in, ushort* __restrict__ out,
                             long n4) {
    long i = (long)blockIdx.x * blockDim.x + threadIdx.x;
    long stride = (long)gridDim.x * blockDim.x;
    for (; i < n4; i += stride) {
        float4 v = *reinterpret_cast<const float4*>(in + i * 4);
        ushort4 r;
        r.x = f2bf(v.x); r.y = f2bf(v.y); r.z = f2bf(v.z); r.w = f2bf(v.w);
        *reinterpret_cast<ushort4*>(out + i * 4) = r;
    }
}

// Wt[n][k] = bf16( k<128 ? Wl[k][n] : Wr[k-128][n] ), n >= ncols -> 0
__global__ void cvt_w(const float* __restrict__ Wl, const float* __restrict__ Wr,
                      ushort* __restrict__ Wt, int ncols) {
    int n = blockIdx.x;
    int k = threadIdx.x;
    float v = 0.0f;
    if (n < ncols)
        v = (k < 128) ? Wl[(size_t)k * ncols + n] : Wr[(size_t)(k - 128) * ncols + n];
    Wt[(size_t)n * 256 + k] = f2bf(v);
}

// ---------------- gather-based mean aggregation (bf16) ----------------
__global__ __launch_bounds__(256) void aggregate_mean_bf(
    const ushort* __restrict__ feat, const int* __restrict__ csr,
    const int* __restrict__ cursor, ushort* __restrict__ out) {
    int node = blockIdx.x * 4 + (threadIdx.x >> 6);
    if (node >= N_NODES) return;
    int lane = threadIdx.x & 63;
    int beg = (node > 0) ? cursor[node - 1] : 0;
    int end = cursor[node];
    float ax0 = 0, ay0 = 0, ax1 = 0, ay1 = 0;
    float ax2 = 0, ay2 = 0, ax3 = 0, ay3 = 0;
    int e = beg;
    for (; e + 4 <= end; e += 4) {
        int s0 = csr[e], s1 = csr[e + 1], s2 = csr[e + 2], s3 = csr[e + 3];
        ushort2 v0 = *reinterpret_cast<const ushort2*>(feat + (size_t)s0 * 128 + lane * 2);
        ushort2 v1 = *reinterpret_cast<const ushort2*>(feat + (size_t)s1 * 128 + lane * 2);
        ushort2 v2 = *reinterpret_cast<const ushort2*>(feat + (size_t)s2 * 128 + lane * 2);
        ushort2 v3 = *reinterpret_cast<const ushort2*>(feat + (size_t)s3 * 128 + lane * 2);
        ax0 += bf2f(v0.x); ay0 += bf2f(v0.y);
        ax1 += bf2f(v1.x); ay1 += bf2f(v1.y);
        ax2 += bf2f(v2.x); ay2 += bf2f(v2.y);
        ax3 += bf2f(v3.x); ay3 += bf2f(v3.y);
    }
    for (; e < end; ++e) {
        ushort2 v = *reinterpret_cast<const ushort2*>(feat + (size_t)csr[e] * 128 + lane * 2);
        ax0 += bf2f(v.x); ay0 += bf2f(v.y);
    }
    int deg = end - beg;
    float inv = (deg > 0) ? (1.0f / (float)deg) : 0.0f;
    ushort2 r;
    r.x = f2bf((ax0 + ax1 + ax2 + ax3) * inv);
    r.y = f2bf((ay0 + ay1 + ay2 + ay3) * inv);
    *reinterpret_cast<ushort2*>(out + (size_t)node * 128 + lane * 2) = r;
}

// ---------------- layer 1 MFMA: h = dropout(relu([agg|x] @ W1' + b1)) ----------------
// 16 rows per wave (1 A-frag), 8 col-frags; 6250 waves for latency hiding.
// Dropout mask precomputed -> epilogue is load + bit-test.
__global__ __launch_bounds__(256) void layer1_mfma(
    const ushort* __restrict__ agg, const ushort* __restrict__ xbf,
    const ushort* __restrict__ Wt, const float* __restrict__ b1,
    const uint32_t* __restrict__ dmask, ushort* __restrict__ h) {
    const int tid = threadIdx.x;
    const int lane = tid & 63;
    const int l15 = lane & 15, kg = lane >> 4;
    const int wid = blockIdx.x * 4 + (tid >> 6);
    const int row_base = wid * 16;
    if (row_base >= N_NODES) return;
    int r0 = row_base + l15;
    int r0c = (r0 < N_NODES) ? r0 : (N_NODES - 1);

    f32x4 acc[8];
    #pragma unroll
    for (int nf = 0; nf < 8; ++nf) acc[nf] = (f32x4){0.f, 0.f, 0.f, 0.f};

    #pragma unroll
    for (int ks = 0; ks < 8; ++ks) {
        const int kglob = ks * 32 + kg * 8;
        const ushort* abase = (kglob < 128) ? agg : xbf;
        const int koff = (kglob < 128) ? kglob : (kglob - 128);
        bf16x8 a0 = *reinterpret_cast<const bf16x8*>(abase + (size_t)r0c * 128 + koff);
        #pragma unroll
        for (int nf = 0; nf < 8; ++nf) {
            bf16x8 b = *reinterpret_cast<const bf16x8*>(
                Wt + (size_t)(nf * 16 + l15) * 256 + ks * 32 + kg * 8);
            acc[nf] = __builtin_amdgcn_mfma_f32_16x16x32_bf16(a0, b, acc[nf], 0, 0, 0);
        }
    }

    #pragma unroll
    for (int r = 0; r < 4; ++r) {
        int row = row_base + kg * 4 + r;
        if (row < N_NODES) {
            uint4 mw = *reinterpret_cast<const uint4*>(dmask + (size_t)row * 4);
            const uint32_t* mwp = reinterpret_cast<const uint32_t*>(&mw);
            #pragma unroll
            for (int nf = 0; nf < 8; ++nf) {
                int col = nf * 16 + l15;
                float v = acc[nf][r] + b1[col];
                v = fmaxf(v, 0.0f) * 2.0f;
                if ((mwp[col >> 5] >> (col & 31)) & 1u) v = 0.0f;
                h[(size_t)row * 128 + col] = f2bf(v);
            }
        }
    }
}

// ---------------- layer 2 MFMA: out = log_softmax([agg|h] @ W2' + b2) ----------------
// 16 rows per wave, 3 col-frags (N padded to 48).
__global__ __launch_bounds__(256) void layer2_mfma(
    const ushort* __restrict__ agg, const ushort* __restrict__ hbf,
    const ushort* __restrict__ Wt2, const float* __restrict__ b2,
    float* __restrict__ out) {
    const int tid = threadIdx.x;
    const int lane = tid & 63;
    const int l15 = lane & 15, kg = lane >> 4;
    const int wid = blockIdx.x * 4 + (tid >> 6);
    const int row_base = wid * 16;
    if (row_base >= N_NODES) return;
    int r0 = row_base + l15;
    int r0c = (r0 < N_NODES) ? r0 : (N_NODES - 1);

    f32x4 acc[3];
    #pragma unroll
    for (int nf = 0; nf < 3; ++nf) acc[nf] = (f32x4){0.f, 0.f, 0.f, 0.f};

    #pragma unroll
    for (int ks = 0; ks < 8; ++ks) {
        const int kglob = ks * 32 + kg * 8;
        const ushort* abase = (kglob < 128) ? agg : hbf;
        const int koff = (kglob < 128) ? kglob : (kglob - 128);
        bf16x8 a0 = *reinterpret_cast<const bf16x8*>(abase + (size_t)r0c * 128 + koff);
        #pragma unroll
        for (int nf = 0; nf < 3; ++nf) {
            bf16x8 b = *reinterpret_cast<const bf16x8*>(
                Wt2 + (size_t)(nf * 16 + l15) * 256 + ks * 32 + kg * 8);
            acc[nf] = __builtin_amdgcn_mfma_f32_16x16x32_bf16(a0, b, acc[nf], 0, 0, 0);
        }
    }

    #pragma unroll
    for (int r = 0; r < 4; ++r) {
        int row = row_base + kg * 4 + r;
        float v[3];
        #pragma unroll
        for (int nf = 0; nf < 3; ++nf) {
            int col = nf * 16 + l15;
            v[nf] = (col < OUT_CH) ? (acc[nf][r] + b2[col]) : -3.0e38f;
        }
        float mx = fmaxf(fmaxf(v[0], v[1]), v[2]);
        #pragma unroll
        for (int s = 1; s < 16; s <<= 1) mx = fmaxf(mx, __shfl_xor(mx, s, 64));
        float se = 0.0f;
        #pragma unroll
        for (int nf = 0; nf < 3; ++nf) {
            int col = nf * 16 + l15;
            if (col < OUT_CH) se += expf(v[nf] - mx);
        }
        #pragma unroll
        for (int s = 1; s < 16; s <<= 1) se += __shfl_xor(se, s, 64);
        float lz = mx + logf(se);
        if (row < N_NODES) {
            #pragma unroll
            for (int nf = 0; nf < 3; ++nf) {
                int col = nf * 16 + l15;
                if (col < OUT_CH)
                    out[(size_t)row * OUT_CH + col] = v[nf] - lz;
            }
        }
    }
}

// ---------------- launch ----------------
extern "C" void kernel_launch(void* const* d_in, const int* in_sizes, int n_in,
                              void* d_out, int out_size, void* d_ws, size_t ws_size,
                              hipStream_t stream) {
    const float* x   = (const float*)d_in[0];
    const void*  ei  = d_in[1];
    const float* W1l = (const float*)d_in[2];
    const float* b1  = (const float*)d_in[3];
    const float* W1r = (const float*)d_in[4];
    const float* W2l = (const float*)d_in[5];
    const float* b2  = (const float*)d_in[6];
    const float* W2r = (const float*)d_in[7];
    float* out = (float*)d_out;

    // ws layout (~101.1 MB, under the 102.9 MB validated in rounds 3/4)
    char* ws = (char*)d_ws;
    int*      flag   = (int*)ws;
    int*      gcnt   = (int*)(ws + 4096);            // 1568 counters, 64B-strided
    int*      bbase  = (int*)(ws + 106496);          // 196 ints
    ushort*   x_bf   = (ushort*)(ws + 131072);       // 25.6 MB
    ushort*   h_bf   = (ushort*)(ws + 131072 + 25600000);
    ushort*   agg_bf = (ushort*)(ws + 131072 + 51200000);
    ushort*   Wt1    = (ushort*)(ws + 131072 + 76800000);       // 64 KB
    ushort*   Wt2    = (ushort*)(ws + 131072 + 76865536);       // 24 KB
    uint2*    gbuf   = (uint2*)(ws + 131072 + 76890112);        // 22.48 MB
    uint32_t* dmask  = (uint32_t*)(ws + 99500032);              // 1.6 MB

    // d_out (16 MB) doubles as CSR scratch; fully consumed before layer2 writes.
    char* ob = (char*)d_out;
    int* csr    = (int*)ob;                        // 6.4 MB
    int* cursor = (int*)(ob + 6400000);            // 400 KB

    zero_i32<<<32, 256, 0, stream>>>(gcnt, NG * NB * 16);
    zero_i32<<<1, 64, 0, stream>>>(flag, 1);
    detect_int64<<<1024, 256, 0, stream>>>((const int*)ei, flag);

    bucket_edges<<<2048, 256, 0, stream>>>(ei, flag, gcnt, gbuf);
    bucket_scan<<<1, 256, 0, stream>>>(gcnt, bbase);
    build_csr<<<NB, 256, 0, stream>>>(gcnt, gbuf, bbase, csr, cursor);

    dropout_mask<<<(N_MASK_WORDS + 255) / 256, 256, 0, stream>>>(dmask);
    cvt_f32_bf16<<<2048, 256, 0, stream>>>(x, x_bf, (long)N_NODES * 128 / 4);
    cvt_w<<<128, 256, 0, stream>>>(W1l, W1r, Wt1, 128);
    cvt_w<<<48, 256, 0, stream>>>(W2l, W2r, Wt2, 40);

    aggregate_mean_bf<<<(N_NODES + 3) / 4, 256, 0, stream>>>(x_bf, csr, cursor, agg_bf);
    layer1_mfma<<<(N_NODES + 63) / 64, 256, 0, stream>>>(agg_bf, x_bf, Wt1, b1, dmask, h_bf);
    aggregate_mean_bf<<<(N_NODES + 3) / 4, 256, 0, stream>>>(h_bf, csr, cursor, agg_bf);
    layer2_mfma<<<(N_NODES + 63) / 64, 256, 0, stream>>>(agg_bf, h_bf, Wt2, b2, out);
}

// Round 8
// 344.000 us; speedup vs baseline: 1.2898x; 1.2898x over previous
//
#include <hip/hip_runtime.h>
#include <stdint.h>
#include <stddef.h>

#define N_NODES 100000
#define N_EDGES 1600000
#define IN_CH 128
#define HID_CH 128
#define OUT_CH 40

#define NB 196            // buckets: b = dst >> 9 (512 nodes each)
#define GCAP 10240        // per-bucket capacity (mean 8163 + 22 sigma)
#define TILE_EDGES 2048   // edges per WG in bucket_edges
#define LCAP 40           // LDS slots per bucket per tile (mean 10.4 + 9 sigma; slow-path fallback)

#define N_MASK_WORDS 400000   // 100000*128/32
#define N_CVT4 3200000        // 100000*128/4

typedef __attribute__((ext_vector_type(8))) short bf16x8;
typedef __attribute__((ext_vector_type(4))) float f32x4;

// ---------------- bf16 helpers ----------------
__device__ __forceinline__ ushort f2bf(float f) {
    uint32_t u = __float_as_uint(f);
    uint32_t r = (u + 0x7FFFu + ((u >> 16) & 1u)) >> 16;   // RNE
    return (ushort)r;
}
__device__ __forceinline__ float bf2f(ushort u) {
    return __uint_as_float(((uint32_t)u) << 16);
}

// ---------------- threefry2x32 (JAX PRNG, key = (0,42)) ----------------
__device__ __forceinline__ uint32_t rotl32(uint32_t x, int r) {
    return (x << r) | (x >> (32 - r));
}

__device__ __forceinline__ void threefry2x32_k42(uint32_t x0, uint32_t x1,
                                                 uint32_t& o0, uint32_t& o1) {
    const uint32_t ks0 = 0u, ks1 = 42u;
    const uint32_t ks2 = 0u ^ 42u ^ 0x1BD11BDAu;
    x0 += ks0; x1 += ks1;
    x0 += x1; x1 = rotl32(x1, 13); x1 ^= x0;
    x0 += x1; x1 = rotl32(x1, 15); x1 ^= x0;
    x0 += x1; x1 = rotl32(x1, 26); x1 ^= x0;
    x0 += x1; x1 = rotl32(x1,  6); x1 ^= x0;
    x0 += ks1; x1 += ks2 + 1u;
    x0 += x1; x1 = rotl32(x1, 17); x1 ^= x0;
    x0 += x1; x1 = rotl32(x1, 29); x1 ^= x0;
    x0 += x1; x1 = rotl32(x1, 16); x1 ^= x0;
    x0 += x1; x1 = rotl32(x1, 24); x1 ^= x0;
    x0 += ks2; x1 += ks0 + 2u;
    x0 += x1; x1 = rotl32(x1, 13); x1 ^= x0;
    x0 += x1; x1 = rotl32(x1, 15); x1 ^= x0;
    x0 += x1; x1 = rotl32(x1, 26); x1 ^= x0;
    x0 += x1; x1 = rotl32(x1,  6); x1 ^= x0;
    x0 += ks0; x1 += ks1 + 3u;
    x0 += x1; x1 = rotl32(x1, 17); x1 ^= x0;
    x0 += x1; x1 = rotl32(x1, 29); x1 ^= x0;
    x0 += x1; x1 = rotl32(x1, 16); x1 ^= x0;
    x0 += x1; x1 = rotl32(x1, 24); x1 ^= x0;
    x0 += ks1; x1 += ks2 + 4u;
    x0 += x1; x1 = rotl32(x1, 13); x1 ^= x0;
    x0 += x1; x1 = rotl32(x1, 15); x1 ^= x0;
    x0 += x1; x1 = rotl32(x1, 26); x1 ^= x0;
    x0 += x1; x1 = rotl32(x1,  6); x1 ^= x0;
    x0 += ks2; x1 += ks0 + 5u;
    o0 = x0; o1 = x1;
}

// ---------------- edge load ----------------
__device__ __forceinline__ void load_edge(const void* ei, bool is32, int e,
                                          int& s, int& d) {
    if (is32) {
        const int* p = (const int*)ei;
        s = p[e]; d = p[N_EDGES + e];
    } else {
        const long long* p = (const long long*)ei;
        s = (int)p[e]; d = (int)p[N_EDGES + e];
    }
}

// ---------------- prep: sampled dtype detect (block 0) + zero gcnt (block 1) --------
// int64 layout: every odd 32-bit word is 0.  int32: odd words are node ids
// (~1e-5 chance of 0 each); 16384 samples -> discrimination is certain.
__global__ __launch_bounds__(256) void prep(const int* __restrict__ ei32,
                                            int* __restrict__ flag,
                                            int* __restrict__ gcnt) {
    const int t = threadIdx.x;
    if (blockIdx.x == 0) {
        __shared__ int red[256];
        int local = 0;
        #pragma unroll
        for (int j = 0; j < 64; ++j) {
            int k = (t * 64 + j) * 97;           // max 1,589,151 < N_EDGES
            local |= ei32[2 * k + 1];
        }
        red[t] = local;
        __syncthreads();
        for (int off = 128; off; off >>= 1) {
            if (t < off) red[t] |= red[t + off];
            __syncthreads();
        }
        if (t == 0) *flag = (red[0] != 0);
    } else {
        for (int i = t; i < NB * 16; i += 256) gcnt[i] = 0;
    }
}

// ---------------- bucketed CSR build, pass 1: LDS-staged append ----------------
// One WG per 2048-edge tile; LDS buckets flushed with ONE global atomic per
// non-empty bucket (~196/WG vs 2048 per-edge) and contiguous 8B*cnt runs.
__global__ __launch_bounds__(256) void bucket_edges(
    const void* __restrict__ ei, const int* __restrict__ flag,
    int* __restrict__ gcnt, uint2* __restrict__ gbuf) {
    __shared__ uint2 lbuf[NB][LCAP];   // 62.7 KB
    __shared__ int lcnt[NB];
    const bool is32 = (*flag != 0);
    const int t = threadIdx.x;
    for (int b = t; b < NB; b += 256) lcnt[b] = 0;
    __syncthreads();
    const int base = blockIdx.x * TILE_EDGES;
    #pragma unroll
    for (int j = 0; j < TILE_EDGES / 256; ++j) {
        int e = base + j * 256 + t;
        if (e < N_EDGES) {
            int s, d;
            load_edge(ei, is32, e, s, d);
            int b = d >> 9;
            int pos = atomicAdd(&lcnt[b], 1);
            if (pos < LCAP) {
                lbuf[b][pos] = make_uint2((uint32_t)s, (uint32_t)d);
            } else {   // overflow slow path (statistically ~never; correctness-preserving)
                int gp = atomicAdd(&gcnt[b * 16], 1);
                gbuf[(size_t)b * GCAP + gp] = make_uint2((uint32_t)s, (uint32_t)d);
            }
        }
    }
    __syncthreads();
    if (t < NB) {
        int cnt = lcnt[t];
        if (cnt > LCAP) cnt = LCAP;
        if (cnt > 0) {
            int gp = atomicAdd(&gcnt[t * 16], cnt);
            uint2* dst = gbuf + (size_t)t * GCAP + gp;
            for (int i = 0; i < cnt; ++i) dst[i] = lbuf[t][i];
        }
    }
}

// exclusive scan of bucket totals (196 values, 1 block)
__global__ void bucket_scan(const int* __restrict__ gcnt, int* __restrict__ bbase) {
    __shared__ int s[256];
    int t = threadIdx.x;
    int tot = (t < NB) ? gcnt[t * 16] : 0;
    s[t] = tot;
    __syncthreads();
    for (int off = 1; off < 256; off <<= 1) {
        int a = (t >= off) ? s[t - off] : 0;
        __syncthreads();
        s[t] += a;
        __syncthreads();
    }
    if (t < NB) bbase[t] = s[t] - tot;   // exclusive
}

// pass 2: one WG per bucket -> exact degrees (histogram), scan, cursor, place.
__global__ __launch_bounds__(256) void build_csr(
    const int* __restrict__ gcnt, const uint2* __restrict__ gbuf,
    const int* __restrict__ bbase, int* __restrict__ csr, int* __restrict__ cursor) {
    __shared__ int hist[512];
    __shared__ int excl[512];
    __shared__ int cur[512];
    __shared__ int psum[256];
    const int b = blockIdx.x;
    const int t = threadIdx.x;
    hist[t] = 0; hist[t + 256] = 0;
    __syncthreads();
    const int base = bbase[b];
    const int cnt = gcnt[b * 16];
    const uint2* src = gbuf + (size_t)b * GCAP;
    for (int i = t; i < cnt; i += 256)
        atomicAdd(&hist[src[i].y & 511], 1);
    __syncthreads();
    int h0 = hist[2 * t], h1 = hist[2 * t + 1];
    psum[t] = h0 + h1;
    __syncthreads();
    int v = psum[t];
    for (int off = 1; off < 256; off <<= 1) {
        int a = (t >= off) ? psum[t - off] : 0;
        __syncthreads();
        psum[t] += a;
        __syncthreads();
    }
    int pex = psum[t] - v;
    excl[2 * t] = pex;
    excl[2 * t + 1] = pex + h0;
    cur[2 * t] = pex;
    cur[2 * t + 1] = pex + h0;
    __syncthreads();
    for (int j = t; j < 512; j += 256) {
        int node = b * 512 + j;
        if (node < N_NODES) cursor[node] = base + excl[j] + hist[j];
    }
    for (int i = t; i < cnt; i += 256) {
        uint2 p = src[i];
        int pos = atomicAdd(&cur[p.y & 511], 1);
        csr[base + pos] = (int)p.x;
    }
}

// ---------------- fused: x -> bf16 conversion + dropout mask precompute ----------------
// mask word w, bit j <-> element idx = w*32+j; bit==1 means DROP.
// (Same bits as validated rounds 3-7: partitionable threefry, o0^o1, MSB.)
__global__ __launch_bounds__(256) void cvt_and_mask(
    const float* __restrict__ in, ushort* __restrict__ out,
    uint32_t* __restrict__ mask) {
    const long gid = (long)blockIdx.x * blockDim.x + threadIdx.x;
    const long stride = (long)gridDim.x * blockDim.x;
    for (long i = gid; i < N_CVT4; i += stride) {
        float4 v = *reinterpret_cast<const float4*>(in + i * 4);
        ushort4 r;
        r.x = f2bf(v.x); r.y = f2bf(v.y); r.z = f2bf(v.z); r.w = f2bf(v.w);
        *reinterpret_cast<ushort4*>(out + i * 4) = r;
    }
    for (long w = gid; w < N_MASK_WORDS; w += stride) {
        uint32_t m = 0;
        #pragma unroll 4
        for (int j = 0; j < 32; ++j) {
            uint32_t o0, o1;
            threefry2x32_k42(0u, (uint32_t)w * 32u + j, o0, o1);
            m |= ((o0 ^ o1) >> 31) << j;
        }
        mask[w] = m;
    }
}

// Wt[n][k] = bf16( k<128 ? Wl[k][n] : Wr[k-128][n] ); blocks 0-127: W1, 128-175: W2
__global__ void cvt_w2(const float* __restrict__ W1l, const float* __restrict__ W1r,
                       const float* __restrict__ W2l, const float* __restrict__ W2r,
                       ushort* __restrict__ Wt1, ushort* __restrict__ Wt2) {
    int blk = blockIdx.x;
    int k = threadIdx.x;
    if (blk < 128) {
        int n = blk;
        float v = (k < 128) ? W1l[(size_t)k * 128 + n] : W1r[(size_t)(k - 128) * 128 + n];
        Wt1[(size_t)n * 256 + k] = f2bf(v);
    } else {
        int n = blk - 128;
        float v = 0.0f;
        if (n < OUT_CH)
            v = (k < 128) ? W2l[(size_t)k * 40 + n] : W2r[(size_t)(k - 128) * 40 + n];
        Wt2[(size_t)n * 256 + k] = f2bf(v);
    }
}

// ---------------- gather-based mean aggregation (bf16) ----------------
__global__ __launch_bounds__(256) void aggregate_mean_bf(
    const ushort* __restrict__ feat, const int* __restrict__ csr,
    const int* __restrict__ cursor, ushort* __restrict__ out) {
    int node = blockIdx.x * 4 + (threadIdx.x >> 6);
    if (node >= N_NODES) return;
    int lane = threadIdx.x & 63;
    int beg = (node > 0) ? cursor[node - 1] : 0;
    int end = cursor[node];
    float ax0 = 0, ay0 = 0, ax1 = 0, ay1 = 0;
    float ax2 = 0, ay2 = 0, ax3 = 0, ay3 = 0;
    int e = beg;
    for (; e + 4 <= end; e += 4) {
        int s0 = csr[e], s1 = csr[e + 1], s2 = csr[e + 2], s3 = csr[e + 3];
        ushort2 v0 = *reinterpret_cast<const ushort2*>(feat + (size_t)s0 * 128 + lane * 2);
        ushort2 v1 = *reinterpret_cast<const ushort2*>(feat + (size_t)s1 * 128 + lane * 2);
        ushort2 v2 = *reinterpret_cast<const ushort2*>(feat + (size_t)s2 * 128 + lane * 2);
        ushort2 v3 = *reinterpret_cast<const ushort2*>(feat + (size_t)s3 * 128 + lane * 2);
        ax0 += bf2f(v0.x); ay0 += bf2f(v0.y);
        ax1 += bf2f(v1.x); ay1 += bf2f(v1.y);
        ax2 += bf2f(v2.x); ay2 += bf2f(v2.y);
        ax3 += bf2f(v3.x); ay3 += bf2f(v3.y);
    }
    for (; e < end; ++e) {
        ushort2 v = *reinterpret_cast<const ushort2*>(feat + (size_t)csr[e] * 128 + lane * 2);
        ax0 += bf2f(v.x); ay0 += bf2f(v.y);
    }
    int deg = end - beg;
    float inv = (deg > 0) ? (1.0f / (float)deg) : 0.0f;
    ushort2 r;
    r.x = f2bf((ax0 + ax1 + ax2 + ax3) * inv);
    r.y = f2bf((ay0 + ay1 + ay2 + ay3) * inv);
    *reinterpret_cast<ushort2*>(out + (size_t)node * 128 + lane * 2) = r;
}

// ---------------- layer 1 MFMA: h = dropout(relu([agg|x] @ W1' + b1)) ----------------
__global__ __launch_bounds__(256) void layer1_mfma(
    const ushort* __restrict__ agg, const ushort* __restrict__ xbf,
    const ushort* __restrict__ Wt, const float* __restrict__ b1,
    const uint32_t* __restrict__ dmask, ushort* __restrict__ h) {
    const int tid = threadIdx.x;
    const int lane = tid & 63;
    const int l15 = lane & 15, kg = lane >> 4;
    const int wid = blockIdx.x * 4 + (tid >> 6);
    const int row_base = wid * 16;
    if (row_base >= N_NODES) return;
    int r0 = row_base + l15;
    int r0c = (r0 < N_NODES) ? r0 : (N_NODES - 1);

    f32x4 acc[8];
    #pragma unroll
    for (int nf = 0; nf < 8; ++nf) acc[nf] = (f32x4){0.f, 0.f, 0.f, 0.f};

    #pragma unroll
    for (int ks = 0; ks < 8; ++ks) {
        const int kglob = ks * 32 + kg * 8;
        const ushort* abase = (kglob < 128) ? agg : xbf;
        const int koff = (kglob < 128) ? kglob : (kglob - 128);
        bf16x8 a0 = *reinterpret_cast<const bf16x8*>(abase + (size_t)r0c * 128 + koff);
        #pragma unroll
        for (int nf = 0; nf < 8; ++nf) {
            bf16x8 b = *reinterpret_cast<const bf16x8*>(
                Wt + (size_t)(nf * 16 + l15) * 256 + ks * 32 + kg * 8);
            acc[nf] = __builtin_amdgcn_mfma_f32_16x16x32_bf16(a0, b, acc[nf], 0, 0, 0);
        }
    }

    #pragma unroll
    for (int r = 0; r < 4; ++r) {
        int row = row_base + kg * 4 + r;
        if (row < N_NODES) {
            uint4 mw = *reinterpret_cast<const uint4*>(dmask + (size_t)row * 4);
            const uint32_t* mwp = reinterpret_cast<const uint32_t*>(&mw);
            #pragma unroll
            for (int nf = 0; nf < 8; ++nf) {
                int col = nf * 16 + l15;
                float v = acc[nf][r] + b1[col];
                v = fmaxf(v, 0.0f) * 2.0f;
                if ((mwp[col >> 5] >> (col & 31)) & 1u) v = 0.0f;
                h[(size_t)row * 128 + col] = f2bf(v);
            }
        }
    }
}

// ---------------- layer 2 MFMA: out = log_softmax([agg|h] @ W2' + b2) ----------------
__global__ __launch_bounds__(256) void layer2_mfma(
    const ushort* __restrict__ agg, const ushort* __restrict__ hbf,
    const ushort* __restrict__ Wt2, const float* __restrict__ b2,
    float* __restrict__ out) {
    const int tid = threadIdx.x;
    const int lane = tid & 63;
    const int l15 = lane & 15, kg = lane >> 4;
    const int wid = blockIdx.x * 4 + (tid >> 6);
    const int row_base = wid * 16;
    if (row_base >= N_NODES) return;
    int r0 = row_base + l15;
    int r0c = (r0 < N_NODES) ? r0 : (N_NODES - 1);

    f32x4 acc[3];
    #pragma unroll
    for (int nf = 0; nf < 3; ++nf) acc[nf] = (f32x4){0.f, 0.f, 0.f, 0.f};

    #pragma unroll
    for (int ks = 0; ks < 8; ++ks) {
        const int kglob = ks * 32 + kg * 8;
        const ushort* abase = (kglob < 128) ? agg : hbf;
        const int koff = (kglob < 128) ? kglob : (kglob - 128);
        bf16x8 a0 = *reinterpret_cast<const bf16x8*>(abase + (size_t)r0c * 128 + koff);
        #pragma unroll
        for (int nf = 0; nf < 3; ++nf) {
            bf16x8 b = *reinterpret_cast<const bf16x8*>(
                Wt2 + (size_t)(nf * 16 + l15) * 256 + ks * 32 + kg * 8);
            acc[nf] = __builtin_amdgcn_mfma_f32_16x16x32_bf16(a0, b, acc[nf], 0, 0, 0);
        }
    }

    #pragma unroll
    for (int r = 0; r < 4; ++r) {
        int row = row_base + kg * 4 + r;
        float v[3];
        #pragma unroll
        for (int nf = 0; nf < 3; ++nf) {
            int col = nf * 16 + l15;
            v[nf] = (col < OUT_CH) ? (acc[nf][r] + b2[col]) : -3.0e38f;
        }
        float mx = fmaxf(fmaxf(v[0], v[1]), v[2]);
        #pragma unroll
        for (int s = 1; s < 16; s <<= 1) mx = fmaxf(mx, __shfl_xor(mx, s, 64));
        float se = 0.0f;
        #pragma unroll
        for (int nf = 0; nf < 3; ++nf) {
            int col = nf * 16 + l15;
            if (col < OUT_CH) se += expf(v[nf] - mx);
        }
        #pragma unroll
        for (int s = 1; s < 16; s <<= 1) se += __shfl_xor(se, s, 64);
        float lz = mx + logf(se);
        if (row < N_NODES) {
            #pragma unroll
            for (int nf = 0; nf < 3; ++nf) {
                int col = nf * 16 + l15;
                if (col < OUT_CH)
                    out[(size_t)row * OUT_CH + col] = v[nf] - lz;
            }
        }
    }
}

// ---------------- launch ----------------
extern "C" void kernel_launch(void* const* d_in, const int* in_sizes, int n_in,
                              void* d_out, int out_size, void* d_ws, size_t ws_size,
                              hipStream_t stream) {
    const float* x   = (const float*)d_in[0];
    const void*  ei  = d_in[1];
    const float* W1l = (const float*)d_in[2];
    const float* b1  = (const float*)d_in[3];
    const float* W1r = (const float*)d_in[4];
    const float* W2l = (const float*)d_in[5];
    const float* b2  = (const float*)d_in[6];
    const float* W2r = (const float*)d_in[7];
    float* out = (float*)d_out;

    // ws layout (~94.7 MB, under the ~101 MB validated in earlier rounds)
    char* ws = (char*)d_ws;
    int*      flag   = (int*)ws;
    int*      gcnt   = (int*)(ws + 4096);                       // NB*16 ints, 64B-strided
    int*      bbase  = (int*)(ws + 106496);                     // 196 ints
    ushort*   x_bf   = (ushort*)(ws + 131072);                  // 25.6 MB
    ushort*   h_bf   = (ushort*)(ws + 131072 + 25600000);       // 25.6 MB
    ushort*   agg_bf = (ushort*)(ws + 131072 + 51200000);       // 25.6 MB
    ushort*   Wt1    = (ushort*)(ws + 131072 + 76800000);       // 64 KB
    ushort*   Wt2    = (ushort*)(ws + 131072 + 76865536);       // 24 KB
    uint2*    gbuf   = (uint2*)(ws + 77021184);                 // 16.06 MB (196*10240*8)
    uint32_t* dmask  = (uint32_t*)(ws + 93077504);              // 1.6 MB (end ~94.7 MB)

    // d_out (16 MB) doubles as CSR scratch; fully consumed before layer2 writes.
    char* ob = (char*)d_out;
    int* csr    = (int*)ob;                        // 6.4 MB
    int* cursor = (int*)(ob + 6400000);            // 400 KB

    prep<<<2, 256, 0, stream>>>((const int*)ei, flag, gcnt);
    bucket_edges<<<(N_EDGES + TILE_EDGES - 1) / TILE_EDGES, 256, 0, stream>>>(
        ei, flag, gcnt, gbuf);
    bucket_scan<<<1, 256, 0, stream>>>(gcnt, bbase);
    build_csr<<<NB, 256, 0, stream>>>(gcnt, gbuf, bbase, csr, cursor);

    cvt_and_mask<<<2048, 256, 0, stream>>>(x, x_bf, dmask);
    cvt_w2<<<176, 256, 0, stream>>>(W1l, W1r, W2l, W2r, Wt1, Wt2);

    aggregate_mean_bf<<<(N_NODES + 3) / 4, 256, 0, stream>>>(x_bf, csr, cursor, agg_bf);
    layer1_mfma<<<(N_NODES + 63) / 64, 256, 0, stream>>>(agg_bf, x_bf, Wt1, b1, dmask, h_bf);
    aggregate_mean_bf<<<(N_NODES + 3) / 4, 256, 0, stream>>>(h_bf, csr, cursor, agg_bf);
    layer2_mfma<<<(N_NODES + 63) / 64, 256, 0, stream>>>(agg_bf, h_bf, Wt2, b2, out);
}

// Round 9
// 323.113 us; speedup vs baseline: 1.3731x; 1.0646x over previous
//
#include <hip/hip_runtime.h>
#include <stdint.h>
#include <stddef.h>

#define N_NODES 100000
#define N_EDGES 1600000
#define IN_CH 128
#define HID_CH 128
#define OUT_CH 40

#define NB 196            // buckets: b = dst >> 9 (512 nodes each)
#define GCAP 10240        // per-bucket capacity (mean 8163 + 22 sigma)
#define TILE_EDGES 2048   // edges per WG in bucket_edges
#define LCAP 40           // LDS slots per bucket per tile (mean 10.4 + 9 sigma; slow-path fallback)

#define N_MASK_WORDS 400000   // 100000*128/32
#define N_CVT4 3200000        // 100000*128/4

typedef __attribute__((ext_vector_type(8))) short bf16x8;
typedef __attribute__((ext_vector_type(8))) unsigned short u16x8;
typedef __attribute__((ext_vector_type(4))) float f32x4;

// ---------------- bf16 helpers ----------------
__device__ __forceinline__ ushort f2bf(float f) {
    uint32_t u = __float_as_uint(f);
    uint32_t r = (u + 0x7FFFu + ((u >> 16) & 1u)) >> 16;   // RNE
    return (ushort)r;
}
__device__ __forceinline__ float bf2f(ushort u) {
    return __uint_as_float(((uint32_t)u) << 16);
}

// ---------------- threefry2x32 (JAX PRNG, key = (0,42)) ----------------
__device__ __forceinline__ uint32_t rotl32(uint32_t x, int r) {
    return (x << r) | (x >> (32 - r));
}

__device__ __forceinline__ void threefry2x32_k42(uint32_t x0, uint32_t x1,
                                                 uint32_t& o0, uint32_t& o1) {
    const uint32_t ks0 = 0u, ks1 = 42u;
    const uint32_t ks2 = 0u ^ 42u ^ 0x1BD11BDAu;
    x0 += ks0; x1 += ks1;
    x0 += x1; x1 = rotl32(x1, 13); x1 ^= x0;
    x0 += x1; x1 = rotl32(x1, 15); x1 ^= x0;
    x0 += x1; x1 = rotl32(x1, 26); x1 ^= x0;
    x0 += x1; x1 = rotl32(x1,  6); x1 ^= x0;
    x0 += ks1; x1 += ks2 + 1u;
    x0 += x1; x1 = rotl32(x1, 17); x1 ^= x0;
    x0 += x1; x1 = rotl32(x1, 29); x1 ^= x0;
    x0 += x1; x1 = rotl32(x1, 16); x1 ^= x0;
    x0 += x1; x1 = rotl32(x1, 24); x1 ^= x0;
    x0 += ks2; x1 += ks0 + 2u;
    x0 += x1; x1 = rotl32(x1, 13); x1 ^= x0;
    x0 += x1; x1 = rotl32(x1, 15); x1 ^= x0;
    x0 += x1; x1 = rotl32(x1, 26); x1 ^= x0;
    x0 += x1; x1 = rotl32(x1,  6); x1 ^= x0;
    x0 += ks0; x1 += ks1 + 3u;
    x0 += x1; x1 = rotl32(x1, 17); x1 ^= x0;
    x0 += x1; x1 = rotl32(x1, 29); x1 ^= x0;
    x0 += x1; x1 = rotl32(x1, 16); x1 ^= x0;
    x0 += x1; x1 = rotl32(x1, 24); x1 ^= x0;
    x0 += ks1; x1 += ks2 + 4u;
    x0 += x1; x1 = rotl32(x1, 13); x1 ^= x0;
    x0 += x1; x1 = rotl32(x1, 15); x1 ^= x0;
    x0 += x1; x1 = rotl32(x1, 26); x1 ^= x0;
    x0 += x1; x1 = rotl32(x1,  6); x1 ^= x0;
    x0 += ks2; x1 += ks0 + 5u;
    o0 = x0; o1 = x1;
}

// ---------------- edge load ----------------
__device__ __forceinline__ void load_edge(const void* ei, bool is32, int e,
                                          int& s, int& d) {
    if (is32) {
        const int* p = (const int*)ei;
        s = p[e]; d = p[N_EDGES + e];
    } else {
        const long long* p = (const long long*)ei;
        s = (int)p[e]; d = (int)p[N_EDGES + e];
    }
}

// ---------------- prep: sampled dtype detect (block 0) + zero gcnt (block 1) --------
__global__ __launch_bounds__(256) void prep(const int* __restrict__ ei32,
                                            int* __restrict__ flag,
                                            int* __restrict__ gcnt) {
    const int t = threadIdx.x;
    if (blockIdx.x == 0) {
        __shared__ int red[256];
        int local = 0;
        #pragma unroll
        for (int j = 0; j < 64; ++j) {
            int k = (t * 64 + j) * 97;           // max 1,589,151 < N_EDGES
            local |= ei32[2 * k + 1];
        }
        red[t] = local;
        __syncthreads();
        for (int off = 128; off; off >>= 1) {
            if (t < off) red[t] |= red[t + off];
            __syncthreads();
        }
        if (t == 0) *flag = (red[0] != 0);
    } else {
        for (int i = t; i < NB * 16; i += 256) gcnt[i] = 0;
    }
}

// ---------------- bucketed CSR build, pass 1: LDS-staged append ----------------
__global__ __launch_bounds__(256) void bucket_edges(
    const void* __restrict__ ei, const int* __restrict__ flag,
    int* __restrict__ gcnt, uint2* __restrict__ gbuf) {
    __shared__ uint2 lbuf[NB][LCAP];   // 62.7 KB
    __shared__ int lcnt[NB];
    const bool is32 = (*flag != 0);
    const int t = threadIdx.x;
    for (int b = t; b < NB; b += 256) lcnt[b] = 0;
    __syncthreads();
    const int base = blockIdx.x * TILE_EDGES;
    #pragma unroll
    for (int j = 0; j < TILE_EDGES / 256; ++j) {
        int e = base + j * 256 + t;
        if (e < N_EDGES) {
            int s, d;
            load_edge(ei, is32, e, s, d);
            int b = d >> 9;
            int pos = atomicAdd(&lcnt[b], 1);
            if (pos < LCAP) {
                lbuf[b][pos] = make_uint2((uint32_t)s, (uint32_t)d);
            } else {   // overflow slow path (statistically ~never; correctness-preserving)
                int gp = atomicAdd(&gcnt[b * 16], 1);
                gbuf[(size_t)b * GCAP + gp] = make_uint2((uint32_t)s, (uint32_t)d);
            }
        }
    }
    __syncthreads();
    if (t < NB) {
        int cnt = lcnt[t];
        if (cnt > LCAP) cnt = LCAP;
        if (cnt > 0) {
            int gp = atomicAdd(&gcnt[t * 16], cnt);
            uint2* dst = gbuf + (size_t)t * GCAP + gp;
            for (int i = 0; i < cnt; ++i) dst[i] = lbuf[t][i];
        }
    }
}

// exclusive scan of bucket totals (196 values, 1 block)
__global__ void bucket_scan(const int* __restrict__ gcnt, int* __restrict__ bbase) {
    __shared__ int s[256];
    int t = threadIdx.x;
    int tot = (t < NB) ? gcnt[t * 16] : 0;
    s[t] = tot;
    __syncthreads();
    for (int off = 1; off < 256; off <<= 1) {
        int a = (t >= off) ? s[t - off] : 0;
        __syncthreads();
        s[t] += a;
        __syncthreads();
    }
    if (t < NB) bbase[t] = s[t] - tot;   // exclusive
}

// pass 2: one WG per bucket -> exact degrees (histogram), scan, cursor, place.
__global__ __launch_bounds__(256) void build_csr(
    const int* __restrict__ gcnt, const uint2* __restrict__ gbuf,
    const int* __restrict__ bbase, int* __restrict__ csr, int* __restrict__ cursor) {
    __shared__ int hist[512];
    __shared__ int excl[512];
    __shared__ int cur[512];
    __shared__ int psum[256];
    const int b = blockIdx.x;
    const int t = threadIdx.x;
    hist[t] = 0; hist[t + 256] = 0;
    __syncthreads();
    const int base = bbase[b];
    const int cnt = gcnt[b * 16];
    const uint2* src = gbuf + (size_t)b * GCAP;
    for (int i = t; i < cnt; i += 256)
        atomicAdd(&hist[src[i].y & 511], 1);
    __syncthreads();
    int h0 = hist[2 * t], h1 = hist[2 * t + 1];
    psum[t] = h0 + h1;
    __syncthreads();
    int v = psum[t];
    for (int off = 1; off < 256; off <<= 1) {
        int a = (t >= off) ? psum[t - off] : 0;
        __syncthreads();
        psum[t] += a;
        __syncthreads();
    }
    int pex = psum[t] - v;
    excl[2 * t] = pex;
    excl[2 * t + 1] = pex + h0;
    cur[2 * t] = pex;
    cur[2 * t + 1] = pex + h0;
    __syncthreads();
    for (int j = t; j < 512; j += 256) {
        int node = b * 512 + j;
        if (node < N_NODES) cursor[node] = base + excl[j] + hist[j];
    }
    for (int i = t; i < cnt; i += 256) {
        uint2 p = src[i];
        int pos = atomicAdd(&cur[p.y & 511], 1);
        csr[base + pos] = (int)p.x;
    }
}

// ---------------- fused: x -> bf16 conversion + dropout mask precompute ----------------
__global__ __launch_bounds__(256) void cvt_and_mask(
    const float* __restrict__ in, ushort* __restrict__ out,
    uint32_t* __restrict__ mask) {
    const long gid = (long)blockIdx.x * blockDim.x + threadIdx.x;
    const long stride = (long)gridDim.x * blockDim.x;
    for (long i = gid; i < N_CVT4; i += stride) {
        float4 v = *reinterpret_cast<const float4*>(in + i * 4);
        ushort4 r;
        r.x = f2bf(v.x); r.y = f2bf(v.y); r.z = f2bf(v.z); r.w = f2bf(v.w);
        *reinterpret_cast<ushort4*>(out + i * 4) = r;
    }
    for (long w = gid; w < N_MASK_WORDS; w += stride) {
        uint32_t m = 0;
        #pragma unroll 4
        for (int j = 0; j < 32; ++j) {
            uint32_t o0, o1;
            threefry2x32_k42(0u, (uint32_t)w * 32u + j, o0, o1);
            m |= ((o0 ^ o1) >> 31) << j;
        }
        mask[w] = m;
    }
}

// Wt[n][k] = bf16( k<128 ? Wl[k][n] : Wr[k-128][n] ); blocks 0-127: W1, 128-175: W2
__global__ void cvt_w2(const float* __restrict__ W1l, const float* __restrict__ W1r,
                       const float* __restrict__ W2l, const float* __restrict__ W2r,
                       ushort* __restrict__ Wt1, ushort* __restrict__ Wt2) {
    int blk = blockIdx.x;
    int k = threadIdx.x;
    if (blk < 128) {
        int n = blk;
        float v = (k < 128) ? W1l[(size_t)k * 128 + n] : W1r[(size_t)(k - 128) * 128 + n];
        Wt1[(size_t)n * 256 + k] = f2bf(v);
    } else {
        int n = blk - 128;
        float v = 0.0f;
        if (n < OUT_CH)
            v = (k < 128) ? W2l[(size_t)k * 40 + n] : W2r[(size_t)(k - 128) * 40 + n];
        Wt2[(size_t)n * 256 + k] = f2bf(v);
    }
}

// ---------------- gather-based mean aggregation (bf16, 16B/lane) ----------------
// One wave per node; lane = (g, c): g = edge subgroup (4 edges in parallel),
// c = col group (8 channels, 16B load).  Unroll-2 -> 8 edges / 2KB in flight.
// Epilogue: shfl_xor(16,32) sums subgroups; g==0 stores ushort8.
__global__ __launch_bounds__(256) void aggregate_mean_bf(
    const ushort* __restrict__ feat, const int* __restrict__ csr,
    const int* __restrict__ cursor, ushort* __restrict__ out) {
    int node = blockIdx.x * 4 + (threadIdx.x >> 6);
    if (node >= N_NODES) return;
    const int lane = threadIdx.x & 63;
    const int g = lane >> 4;        // 0..3 edge subgroup
    const int c = lane & 15;        // col group: channels c*8..c*8+7
    const int beg = (node > 0) ? cursor[node - 1] : 0;
    const int end = cursor[node];

    float acc[8];
    #pragma unroll
    for (int j = 0; j < 8; ++j) acc[j] = 0.0f;

    int e = beg + g;
    for (; e + 4 < end; e += 8) {
        int s0 = csr[e];
        int s1 = csr[e + 4];
        bf16x8 v0 = *reinterpret_cast<const bf16x8*>(feat + (size_t)s0 * 128 + c * 8);
        bf16x8 v1 = *reinterpret_cast<const bf16x8*>(feat + (size_t)s1 * 128 + c * 8);
        #pragma unroll
        for (int j = 0; j < 8; ++j) acc[j] += bf2f((ushort)v0[j]);
        #pragma unroll
        for (int j = 0; j < 8; ++j) acc[j] += bf2f((ushort)v1[j]);
    }
    if (e < end) {
        int s0 = csr[e];
        bf16x8 v0 = *reinterpret_cast<const bf16x8*>(feat + (size_t)s0 * 128 + c * 8);
        #pragma unroll
        for (int j = 0; j < 8; ++j) acc[j] += bf2f((ushort)v0[j]);
    }

    // sum the 4 edge subgroups (lanes with equal c)
    #pragma unroll
    for (int j = 0; j < 8; ++j) {
        acc[j] += __shfl_xor(acc[j], 16, 64);
        acc[j] += __shfl_xor(acc[j], 32, 64);
    }

    if (g == 0) {
        int deg = end - beg;
        float inv = (deg > 0) ? (1.0f / (float)deg) : 0.0f;
        u16x8 r;
        #pragma unroll
        for (int j = 0; j < 8; ++j) r[j] = f2bf(acc[j] * inv);
        *reinterpret_cast<u16x8*>(out + (size_t)node * 128 + c * 8) = r;
    }
}

// ---------------- layer 1 MFMA: h = dropout(relu([agg|x] @ W1' + b1)) ----------------
__global__ __launch_bounds__(256) void layer1_mfma(
    const ushort* __restrict__ agg, const ushort* __restrict__ xbf,
    const ushort* __restrict__ Wt, const float* __restrict__ b1,
    const uint32_t* __restrict__ dmask, ushort* __restrict__ h) {
    const int tid = threadIdx.x;
    const int lane = tid & 63;
    const int l15 = lane & 15, kg = lane >> 4;
    const int wid = blockIdx.x * 4 + (tid >> 6);
    const int row_base = wid * 16;
    if (row_base >= N_NODES) return;
    int r0 = row_base + l15;
    int r0c = (r0 < N_NODES) ? r0 : (N_NODES - 1);

    f32x4 acc[8];
    #pragma unroll
    for (int nf = 0; nf < 8; ++nf) acc[nf] = (f32x4){0.f, 0.f, 0.f, 0.f};

    #pragma unroll
    for (int ks = 0; ks < 8; ++ks) {
        const int kglob = ks * 32 + kg * 8;
        const ushort* abase = (kglob < 128) ? agg : xbf;
        const int koff = (kglob < 128) ? kglob : (kglob - 128);
        bf16x8 a0 = *reinterpret_cast<const bf16x8*>(abase + (size_t)r0c * 128 + koff);
        #pragma unroll
        for (int nf = 0; nf < 8; ++nf) {
            bf16x8 b = *reinterpret_cast<const bf16x8*>(
                Wt + (size_t)(nf * 16 + l15) * 256 + ks * 32 + kg * 8);
            acc[nf] = __builtin_amdgcn_mfma_f32_16x16x32_bf16(a0, b, acc[nf], 0, 0, 0);
        }
    }

    #pragma unroll
    for (int r = 0; r < 4; ++r) {
        int row = row_base + kg * 4 + r;
        if (row < N_NODES) {
            uint4 mw = *reinterpret_cast<const uint4*>(dmask + (size_t)row * 4);
            const uint32_t* mwp = reinterpret_cast<const uint32_t*>(&mw);
            #pragma unroll
            for (int nf = 0; nf < 8; ++nf) {
                int col = nf * 16 + l15;
                float v = acc[nf][r] + b1[col];
                v = fmaxf(v, 0.0f) * 2.0f;
                if ((mwp[col >> 5] >> (col & 31)) & 1u) v = 0.0f;
                h[(size_t)row * 128 + col] = f2bf(v);
            }
        }
    }
}

// ---------------- layer 2 MFMA: out = log_softmax([agg|h] @ W2' + b2) ----------------
__global__ __launch_bounds__(256) void layer2_mfma(
    const ushort* __restrict__ agg, const ushort* __restrict__ hbf,
    const ushort* __restrict__ Wt2, const float* __restrict__ b2,
    float* __restrict__ out) {
    const int tid = threadIdx.x;
    const int lane = tid & 63;
    const int l15 = lane & 15, kg = lane >> 4;
    const int wid = blockIdx.x * 4 + (tid >> 6);
    const int row_base = wid * 16;
    if (row_base >= N_NODES) return;
    int r0 = row_base + l15;
    int r0c = (r0 < N_NODES) ? r0 : (N_NODES - 1);

    f32x4 acc[3];
    #pragma unroll
    for (int nf = 0; nf < 3; ++nf) acc[nf] = (f32x4){0.f, 0.f, 0.f, 0.f};

    #pragma unroll
    for (int ks = 0; ks < 8; ++ks) {
        const int kglob = ks * 32 + kg * 8;
        const ushort* abase = (kglob < 128) ? agg : hbf;
        const int koff = (kglob < 128) ? kglob : (kglob - 128);
        bf16x8 a0 = *reinterpret_cast<const bf16x8*>(abase + (size_t)r0c * 128 + koff);
        #pragma unroll
        for (int nf = 0; nf < 3; ++nf) {
            bf16x8 b = *reinterpret_cast<const bf16x8*>(
                Wt2 + (size_t)(nf * 16 + l15) * 256 + ks * 32 + kg * 8);
            acc[nf] = __builtin_amdgcn_mfma_f32_16x16x32_bf16(a0, b, acc[nf], 0, 0, 0);
        }
    }

    #pragma unroll
    for (int r = 0; r < 4; ++r) {
        int row = row_base + kg * 4 + r;
        float v[3];
        #pragma unroll
        for (int nf = 0; nf < 3; ++nf) {
            int col = nf * 16 + l15;
            v[nf] = (col < OUT_CH) ? (acc[nf][r] + b2[col]) : -3.0e38f;
        }
        float mx = fmaxf(fmaxf(v[0], v[1]), v[2]);
        #pragma unroll
        for (int s = 1; s < 16; s <<= 1) mx = fmaxf(mx, __shfl_xor(mx, s, 64));
        float se = 0.0f;
        #pragma unroll
        for (int nf = 0; nf < 3; ++nf) {
            int col = nf * 16 + l15;
            if (col < OUT_CH) se += expf(v[nf] - mx);
        }
        #pragma unroll
        for (int s = 1; s < 16; s <<= 1) se += __shfl_xor(se, s, 64);
        float lz = mx + logf(se);
        if (row < N_NODES) {
            #pragma unroll
            for (int nf = 0; nf < 3; ++nf) {
                int col = nf * 16 + l15;
                if (col < OUT_CH)
                    out[(size_t)row * OUT_CH + col] = v[nf] - lz;
            }
        }
    }
}

// ---------------- launch ----------------
extern "C" void kernel_launch(void* const* d_in, const int* in_sizes, int n_in,
                              void* d_out, int out_size, void* d_ws, size_t ws_size,
                              hipStream_t stream) {
    const float* x   = (const float*)d_in[0];
    const void*  ei  = d_in[1];
    const float* W1l = (const float*)d_in[2];
    const float* b1  = (const float*)d_in[3];
    const float* W1r = (const float*)d_in[4];
    const float* W2l = (const float*)d_in[5];
    const float* b2  = (const float*)d_in[6];
    const float* W2r = (const float*)d_in[7];
    float* out = (float*)d_out;

    // ws layout (~94.7 MB)
    char* ws = (char*)d_ws;
    int*      flag   = (int*)ws;
    int*      gcnt   = (int*)(ws + 4096);                       // NB*16 ints, 64B-strided
    int*      bbase  = (int*)(ws + 106496);                     // 196 ints
    ushort*   x_bf   = (ushort*)(ws + 131072);                  // 25.6 MB
    ushort*   h_bf   = (ushort*)(ws + 131072 + 25600000);       // 25.6 MB
    ushort*   agg_bf = (ushort*)(ws + 131072 + 51200000);       // 25.6 MB
    ushort*   Wt1    = (ushort*)(ws + 131072 + 76800000);       // 64 KB
    ushort*   Wt2    = (ushort*)(ws + 131072 + 76865536);       // 24 KB
    uint2*    gbuf   = (uint2*)(ws + 77021184);                 // 16.06 MB (196*10240*8)
    uint32_t* dmask  = (uint32_t*)(ws + 93077504);              // 1.6 MB (end ~94.7 MB)

    // d_out (16 MB) doubles as CSR scratch; fully consumed before layer2 writes.
    char* ob = (char*)d_out;
    int* csr    = (int*)ob;                        // 6.4 MB
    int* cursor = (int*)(ob + 6400000);            // 400 KB

    prep<<<2, 256, 0, stream>>>((const int*)ei, flag, gcnt);
    bucket_edges<<<(N_EDGES + TILE_EDGES - 1) / TILE_EDGES, 256, 0, stream>>>(
        ei, flag, gcnt, gbuf);
    bucket_scan<<<1, 256, 0, stream>>>(gcnt, bbase);
    build_csr<<<NB, 256, 0, stream>>>(gcnt, gbuf, bbase, csr, cursor);

    cvt_and_mask<<<2048, 256, 0, stream>>>(x, x_bf, dmask);
    cvt_w2<<<176, 256, 0, stream>>>(W1l, W1r, W2l, W2r, Wt1, Wt2);

    aggregate_mean_bf<<<(N_NODES + 3) / 4, 256, 0, stream>>>(x_bf, csr, cursor, agg_bf);
    layer1_mfma<<<(N_NODES + 63) / 64, 256, 0, stream>>>(agg_bf, x_bf, Wt1, b1, dmask, h_bf);
    aggregate_mean_bf<<<(N_NODES + 3) / 4, 256, 0, stream>>>(h_bf, csr, cursor, agg_bf);
    layer2_mfma<<<(N_NODES + 63) / 64, 256, 0, stream>>>(agg_bf, h_bf, Wt2, b2, out);
}